// Round 3
// baseline (1340.093 us; speedup 1.0000x reference)
//
#include <hip/hip_runtime.h>

#define DEV __device__ __forceinline__

typedef __attribute__((ext_vector_type(8))) short s16x8;   // 8 bf16 (4 VGPRs) MFMA A/B frag
typedef __attribute__((ext_vector_type(4))) float f32x4;   // MFMA C/D frag
typedef __attribute__((ext_vector_type(4))) unsigned short u16x4;

#define BTOK 8192   // B*S
#define DD   1024
#define FF   4096
#define EE   4

// round-to-nearest-even f32 -> bf16 bits
DEV unsigned short f2bf(float f) {
  unsigned int u = __float_as_uint(f);
  unsigned int r = (u + 0x7FFFu + ((u >> 16) & 1u)) >> 16;
  return (unsigned short)r;
}

// async global->LDS, 16 bytes/lane; LDS dest = wave-uniform base + lane*16
DEV void gld_lds16(const void* g, void* l) {
  __builtin_amdgcn_global_load_lds(
      (const __attribute__((address_space(1))) unsigned int*)g,
      (__attribute__((address_space(3))) unsigned int*)l,
      16, 0, 0);
}

// ---------------------------------------------------------------------------
// 128x128 bf16 MFMA tile mainloop (m97 structure), group-major LDS layout:
//   LDS chunk c = g*128 + r holds A[row r][k-group g (8 elems)].
//   Fragment read addr = quad*2048B + row*16B -> 256B contiguous per 16-lane
//   phase => conflict-free (old row-major layout measured 8.4M conflict cyc).
// A rows optionally gathered through idxA (token compaction).
// ---------------------------------------------------------------------------
DEV void gemm_tile(const unsigned short* __restrict__ A, const int* idxA, int ldA,
                   const unsigned short* __restrict__ B, int ldB,
                   int kStart, int kLen, int tileM, int tileN,
                   unsigned short* As, unsigned short* Bs,
                   f32x4 (&acc)[4][4]) {
  const int t    = threadIdx.x;
  const int lane = t & 63;
  const int wv   = t >> 6;
  const int wm   = (wv & 1) << 6;
  const int wn   = (wv >> 1) << 6;
  const int m16  = lane & 15;
  const int quad = lane >> 4;

  const int r  = t & 127;   // staged row (same for both chunks of this thread)
  const int g0 = t >> 7;    // k-group 0/1; second chunk is g0+2

  const int rowA = idxA ? idxA[tileM + r] : (tileM + r);
  const unsigned short* A0 = A + (size_t)rowA * ldA + kStart + g0 * 8;
  const unsigned short* B0 = B + (size_t)(tileN + r) * ldB + kStart + g0 * 8;

  for (int k0 = 0; k0 < kLen; k0 += 32) {
    __syncthreads();               // protect LDS from previous iteration's readers
    gld_lds16(A0 + k0,      As + t * 8);
    gld_lds16(A0 + k0 + 16, As + (t + 256) * 8);
    gld_lds16(B0 + k0,      Bs + t * 8);
    gld_lds16(B0 + k0 + 16, Bs + (t + 256) * 8);
    __syncthreads();               // drains vmcnt -> staged data visible

    s16x8 aF[4], bF[4];
#pragma unroll
    for (int i = 0; i < 4; ++i) {
      aF[i] = *(const s16x8*)(As + (quad << 10) + ((wm + i * 16 + m16) << 3));
      bF[i] = *(const s16x8*)(Bs + (quad << 10) + ((wn + i * 16 + m16) << 3));
    }
#pragma unroll
    for (int mt = 0; mt < 4; ++mt)
#pragma unroll
      for (int nt = 0; nt < 4; ++nt)
        acc[mt][nt] = __builtin_amdgcn_mfma_f32_16x16x32_bf16(
            aF[mt], bF[nt], acc[mt][nt], 0, 0, 0);
  }
}

// ---------------------------------------------------------------------------
// GEMM1 (gathered): h[p][f] = bf16( sc[p] * relu( xb[idx[p]]@W1[e] + b1[e][f] ) )
// for compact positions p < npad[e]; pad rows have sc=0 -> h row = 0.
// ---------------------------------------------------------------------------
__global__ __launch_bounds__(256) void gemm1_kernel(
    const unsigned short* __restrict__ xb,   // [BTOK][DD]
    const unsigned short* __restrict__ W1T,  // [EE][FF][DD]  (B^T layout)
    const float* __restrict__ b1,            // [EE][FF]
    const float* __restrict__ sc,            // [EE][BTOK] compact scales
    const int* __restrict__ idx,             // [EE][BTOK] compact token idx
    const int* __restrict__ npad,            // [EE] padded active counts
    unsigned short* __restrict__ h,          // [BTOK][FF] (single-expert slot)
    int e) {
  __shared__ __attribute__((aligned(16))) unsigned short As[128 * 32];
  __shared__ __attribute__((aligned(16))) unsigned short Bs[128 * 32];

  const int np    = npad[e];
  const int tileM = blockIdx.y * 128;
  if (tileM >= np) return;                   // block-uniform early exit
  const int tileN = blockIdx.x * 128;

  f32x4 acc[4][4];
#pragma unroll
  for (int i = 0; i < 4; ++i)
#pragma unroll
    for (int j = 0; j < 4; ++j) acc[i][j] = f32x4{0.f, 0.f, 0.f, 0.f};

  gemm_tile(xb, idx + e * BTOK, DD, W1T + (size_t)e * FF * DD, DD,
            0, DD, tileM, tileN, As, Bs, acc);

  const int t = threadIdx.x;
  const int lane = t & 63, wv = t >> 6;
  const int wm = (wv & 1) << 6, wn = (wv >> 1) << 6;
  const int m16 = lane & 15, quad = lane >> 4;
  const float* b1e = b1 + e * FF;
  const float* sce = sc + e * BTOK;

#pragma unroll
  for (int mt = 0; mt < 4; ++mt) {
    const int row = tileM + wm + mt * 16 + quad * 4;   // C/D: row = quad*4 + reg
    const f32x4 cv = *(const f32x4*)(sce + row);       // 16B-aligned (row%4==0)
#pragma unroll
    for (int nt = 0; nt < 4; ++nt) {
      const int col = tileN + wn + nt * 16 + m16;      // C/D: col = lane&15
      const float bb = b1e[col];
      f32x4 v = acc[mt][nt];
      h[(size_t)(row + 0) * FF + col] = f2bf(fmaxf(v[0] + bb, 0.f) * cv[0]);
      h[(size_t)(row + 1) * FF + col] = f2bf(fmaxf(v[1] + bb, 0.f) * cv[1]);
      h[(size_t)(row + 2) * FF + col] = f2bf(fmaxf(v[2] + bb, 0.f) * cv[2]);
      h[(size_t)(row + 3) * FF + col] = f2bf(fmaxf(v[3] + bb, 0.f) * cv[3]);
    }
  }
}

// ---------------------------------------------------------------------------
// GEMM2 (scatter, split-K z=4): out[idx[p]] += h[p]@W2[e] via f32 HW atomics.
// Pad rows (sc=0) have h=0 and idx=0 -> atomic adds of 0 to token 0: harmless.
// ---------------------------------------------------------------------------
__global__ __launch_bounds__(256) void gemm2_kernel(
    const unsigned short* __restrict__ h,    // [BTOK][FF] compact rows
    const unsigned short* __restrict__ W2T,  // [EE][DD][FF]  (B^T layout)
    const int* __restrict__ idx,             // [EE][BTOK]
    const int* __restrict__ npad,            // [EE]
    float* __restrict__ out,                 // [BTOK][DD]
    int e) {
  __shared__ __attribute__((aligned(16))) unsigned short As[128 * 32];
  __shared__ __attribute__((aligned(16))) unsigned short Bs[128 * 32];

  const int np    = npad[e];
  const int tileM = blockIdx.y * 128;
  if (tileM >= np) return;
  const int tileN  = blockIdx.x * 128;
  const int kStart = blockIdx.z * (FF / 4);

  f32x4 acc[4][4];
#pragma unroll
  for (int i = 0; i < 4; ++i)
#pragma unroll
    for (int j = 0; j < 4; ++j) acc[i][j] = f32x4{0.f, 0.f, 0.f, 0.f};

  gemm_tile(h, (const int*)nullptr, FF, W2T + (size_t)e * DD * FF, FF,
            kStart, FF / 4, tileM, tileN, As, Bs, acc);

  const int t = threadIdx.x;
  const int lane = t & 63, wv = t >> 6;
  const int wm = (wv & 1) << 6, wn = (wv >> 1) << 6;
  const int m16 = lane & 15, quad = lane >> 4;
  const int* ide = idx + e * BTOK;

#pragma unroll
  for (int mt = 0; mt < 4; ++mt) {
    const int row = tileM + wm + mt * 16 + quad * 4;
    const int o0 = ide[row + 0], o1 = ide[row + 1];
    const int o2 = ide[row + 2], o3 = ide[row + 3];
#pragma unroll
    for (int nt = 0; nt < 4; ++nt) {
      const int col = tileN + wn + nt * 16 + m16;
      f32x4 v = acc[mt][nt];
      unsafeAtomicAdd(&out[(size_t)o0 * DD + col], v[0]);
      unsafeAtomicAdd(&out[(size_t)o1 * DD + col], v[1]);
      unsafeAtomicAdd(&out[(size_t)o2 * DD + col], v[2]);
      unsafeAtomicAdd(&out[(size_t)o3 * DD + col], v[3]);
    }
  }
}

// ---------------------------------------------------------------------------
// Per-token: u, per-expert weights cE[e][t]; out init with b2 term; x -> bf16.
// ---------------------------------------------------------------------------
__global__ __launch_bounds__(256) void u_kernel(
    const float* __restrict__ x,   // [BTOK][DD]
    const float* __restrict__ Wu,  // [DD]
    const float* __restrict__ bu,  // [1]
    const float* __restrict__ b2,  // [EE][DD]
    float* __restrict__ cE,        // [EE][BTOK]
    float* __restrict__ out,       // [BTOK][DD]
    unsigned short* __restrict__ xb) {  // [BTOK][DD] bf16
  const int tok = blockIdx.x;
  const int tid = threadIdx.x;
  const float* xr = x + (size_t)tok * DD;

  f32x4 xv = ((const f32x4*)xr)[tid];
  f32x4 wv = ((const f32x4*)Wu)[tid];

  // fused f32 -> bf16 conversion (x already in registers)
  u16x4 o = {f2bf(xv[0]), f2bf(xv[1]), f2bf(xv[2]), f2bf(xv[3])};
  ((u16x4*)(xb + (size_t)tok * DD))[tid] = o;

  float s = xv[0] * wv[0] + xv[1] * wv[1] + xv[2] * wv[2] + xv[3] * wv[3];
#pragma unroll
  for (int off = 32; off > 0; off >>= 1) s += __shfl_down(s, off);

  __shared__ float red[4];
  __shared__ float cL[4];
  if ((tid & 63) == 0) red[tid >> 6] = s;
  __syncthreads();
  if (tid == 0) {
    float dot = red[0] + red[1] + red[2] + red[3] + bu[0];
    float u = 1.f / (1.f + expf(-dot));
    float kf = ceilf(u * 4.f);
    kf = fminf(fmaxf(kf, 1.f), 4.f);
    int k = (int)kf;
    int s4 = tok & 3;  // s = tok % 2048; s % 4 == tok % 4
#pragma unroll
    for (int e = 0; e < EE; ++e) {
      int i = ((e - s4) & 3) + 1;
      float ce = (i <= k) ? (u / (float)i) : 0.f;
      cL[e] = ce;
      cE[e * BTOK + tok] = ce;
    }
  }
  __syncthreads();
  const float c0 = cL[0], c1 = cL[1], c2 = cL[2], c3 = cL[3];
#pragma unroll
  for (int d = tid; d < DD; d += 256)
    out[(size_t)tok * DD + d] =
        c0 * b2[d] + c1 * b2[DD + d] + c2 * b2[2 * DD + d] + c3 * b2[3 * DD + d];
}

// ---------------------------------------------------------------------------
// Stable per-expert compaction of active tokens (cE > 0). One block per expert.
// Thread tid scans tokens [tid*32, tid*32+32) -> order-preserving.
// ---------------------------------------------------------------------------
__global__ __launch_bounds__(256) void compact_kernel(
    const float* __restrict__ cE,  // [EE][BTOK]
    int* __restrict__ idx,         // [EE][BTOK]
    float* __restrict__ sc,        // [EE][BTOK]
    int* __restrict__ npad) {      // [EE]
  const int e = blockIdx.x;
  const int tid = threadIdx.x;
  const float* ce = cE + e * BTOK;

  int cnt = 0;
#pragma unroll 4
  for (int j = 0; j < 32; ++j) cnt += (ce[tid * 32 + j] > 0.f) ? 1 : 0;

  // inclusive scan within wave, then wave offsets via LDS
  const int lane = tid & 63, wvi = tid >> 6;
  int inc = cnt;
#pragma unroll
  for (int off = 1; off < 64; off <<= 1) {
    int v = __shfl_up(inc, off);
    if (lane >= off) inc += v;
  }
  __shared__ int wsum[4];
  if (lane == 63) wsum[wvi] = inc;
  __syncthreads();
  int base = 0;
  for (int w = 0; w < wvi; ++w) base += wsum[w];
  int pos = base + inc - cnt;  // exclusive prefix

  for (int j = 0; j < 32; ++j) {
    float v = ce[tid * 32 + j];
    if (v > 0.f) {
      idx[e * BTOK + pos] = tid * 32 + j;
      sc[e * BTOK + pos] = v;
      ++pos;
    }
  }
  __syncthreads();
  const int n = wsum[0] + wsum[1] + wsum[2] + wsum[3];
  const int np = (n + 127) & ~127;
  if (tid == 0) npad[e] = np;
  for (int p = n + tid; p < np; p += 256) {  // pad: token 0 with weight 0
    idx[e * BTOK + p] = 0;
    sc[e * BTOK + p] = 0.f;
  }
}

// ---------------------------------------------------------------------------
// Transpose-convert: src [E][R][C] f32 -> dst [E][C][R] bf16. 32x32 LDS tiles.
// ---------------------------------------------------------------------------
__global__ __launch_bounds__(256) void tpose_kernel(const float* __restrict__ src,
                                                    unsigned short* __restrict__ dst,
                                                    int R, int C) {
  __shared__ float tile[32][33];
  const int e = blockIdx.z;
  const int r0 = blockIdx.y * 32, c0 = blockIdx.x * 32;
  const int tx = threadIdx.x & 31, ty = threadIdx.x >> 5;
  const float* s = src + (size_t)e * R * C;
  unsigned short* d = dst + (size_t)e * C * R;
#pragma unroll
  for (int j = 0; j < 32; j += 8)
    tile[ty + j][tx] = s[(size_t)(r0 + ty + j) * C + (c0 + tx)];
  __syncthreads();
#pragma unroll
  for (int j = 0; j < 32; j += 8)
    d[(size_t)(c0 + ty + j) * R + (r0 + tx)] = f2bf(tile[tx][ty + j]);
}

// ---------------------------------------------------------------------------
extern "C" void kernel_launch(void* const* d_in, const int* in_sizes, int n_in,
                              void* d_out, int out_size, void* d_ws, size_t ws_size,
                              hipStream_t stream) {
  const float* x  = (const float*)d_in[0];
  const float* W1 = (const float*)d_in[1];
  const float* b1 = (const float*)d_in[2];
  const float* W2 = (const float*)d_in[3];
  const float* b2 = (const float*)d_in[4];
  const float* Wu = (const float*)d_in[5];
  const float* bu = (const float*)d_in[6];
  float* out = (float*)d_out;

  // workspace layout (~151.5 MB total)
  char* w = (char*)d_ws;
  unsigned short* xb  = (unsigned short*)w;  w += (size_t)BTOK * DD * 2;     // 16.78 MB
  unsigned short* W1T = (unsigned short*)w;  w += (size_t)EE * DD * FF * 2;  // 33.55 MB
  unsigned short* W2T = (unsigned short*)w;  w += (size_t)EE * FF * DD * 2;  // 33.55 MB
  float* cE  = (float*)w;                    w += (size_t)EE * BTOK * 4;     // 131 KB
  int*   idx = (int*)w;                      w += (size_t)EE * BTOK * 4;     // 131 KB
  float* sc  = (float*)w;                    w += (size_t)EE * BTOK * 4;     // 131 KB
  int*  npad = (int*)w;                      w += 256;
  unsigned short* h = (unsigned short*)w;    // 67.11 MB (single-expert slot)

  u_kernel<<<BTOK, 256, 0, stream>>>(x, Wu, bu, b2, cE, out, xb);
  tpose_kernel<<<dim3(FF / 32, DD / 32, EE), 256, 0, stream>>>(W1, W1T, DD, FF);
  tpose_kernel<<<dim3(DD / 32, FF / 32, EE), 256, 0, stream>>>(W2, W2T, FF, DD);
  compact_kernel<<<EE, 256, 0, stream>>>(cE, idx, sc, npad);

  for (int e = 0; e < EE; ++e) {
    gemm1_kernel<<<dim3(FF / 128, BTOK / 128), 256, 0, stream>>>(
        xb, W1T, b1, sc, idx, npad, h, e);
    gemm2_kernel<<<dim3(DD / 128, BTOK / 128, 4), 256, 0, stream>>>(
        h, W2T, idx, npad, out, e);
  }
}